// Round 8
// baseline (201.718 us; speedup 1.0000x reference)
//
#include <hip/hip_runtime.h>
#include <hip/hip_bf16.h>
#include <stdint.h>

typedef __bf16 bf16_t;
typedef __bf16 bf16x8 __attribute__((ext_vector_type(8)));
typedef __bf16 bf16x4_t __attribute__((ext_vector_type(4)));
typedef float f32x4 __attribute__((ext_vector_type(4)));
typedef float f32x16 __attribute__((ext_vector_type(16)));
typedef unsigned int u32x4 __attribute__((ext_vector_type(4)));

#define B_   2
#define H_   16
#define D_   64
#define LQ_  2048
#define LC_  2048
#define M_   1024

__device__ __forceinline__ void gload_lds16(const void* g, void* l) {
  __builtin_amdgcn_global_load_lds((__attribute__((address_space(1))) unsigned int*)(g),
                                   (__attribute__((address_space(3))) unsigned int*)(l),
                                   16, 0, 0);
}

__device__ __forceinline__ unsigned pack2(float a, float b) {
  __bf16 x = (__bf16)a, y = (__bf16)b;
  unsigned short ux = __builtin_bit_cast(unsigned short, x);
  unsigned short uy = __builtin_bit_cast(unsigned short, y);
  return (unsigned)ux | ((unsigned)uy << 16);
}

// ---------------- fp32 -> bf16 elementwise (vectorized) ----------------
__global__ void cvt_bf16_kernel(const float* __restrict__ in, bf16_t* __restrict__ out, int n4) {
  int i = blockIdx.x * blockDim.x + threadIdx.x;
  if (i < n4) {
    const float4 f = ((const float4*)in)[i];
    bf16x4_t o4;
    o4[0] = (__bf16)f.x; o4[1] = (__bf16)f.y; o4[2] = (__bf16)f.z; o4[3] = (__bf16)f.w;
    ((bf16x4_t*)out)[i] = o4;
  }
}

// ---------------- transpose + convert weights: out[n][k] = in[k][n] ----------------
__global__ void transpose_cvt_kernel(const float* __restrict__ in, bf16_t* __restrict__ out,
                                     int K, int N, int kvperm) {
  __shared__ float tile[32][33];
  const int n0 = blockIdx.x * 32, k0 = blockIdx.y * 32;
  const int tx = threadIdx.x & 31, ty = threadIdx.x >> 5;
  #pragma unroll
  for (int r = ty; r < 32; r += 8)
    tile[r][tx] = in[(size_t)(k0 + r) * N + (n0 + tx)];
  __syncthreads();
  #pragma unroll
  for (int r = ty; r < 32; r += 8) {
    const int n = n0 + r;
    const int orow = kvperm ? ((n & ~127) | ((n & 1) << 6) | ((n >> 1) & 63)) : n;
    out[(size_t)orow * K + (k0 + tx)] = (__bf16)tile[tx][r];
  }
}

// ---------------- GEMM: C[M,N] = A[M,K] @ Bt[N,K]^T, m97 structure ----------------
template <int EPI>
__global__ __launch_bounds__(256)
void gemm_bt_kernel(const bf16_t* __restrict__ A, const bf16_t* __restrict__ Bt,
                    const float* __restrict__ bias,
                    void* __restrict__ out0, void* __restrict__ out1,
                    int N, int K) {
  __shared__ __attribute__((aligned(16))) bf16_t ldsA[128 * 64];
  __shared__ __attribute__((aligned(16))) bf16_t ldsB[128 * 64];
  const int tid  = threadIdx.x;
  const int wave = tid >> 6, lane = tid & 63;
  const int m0 = blockIdx.y * 128, n0 = blockIdx.x * 128;
  const int wr = wave >> 1, wc = wave & 1;
  const int lrow = lane & 15, lk = (lane >> 4) * 8;
  const int srow = lane >> 3, scol = (lane & 7) * 8;

  f32x4 acc[4][4] = {};

  for (int k0 = 0; k0 < K; k0 += 64) {
    __syncthreads();
    #pragma unroll
    for (int i = 0; i < 4; ++i) {
      const int c = wave * 4 + i;
      const int row = c * 8 + srow;
      gload_lds16(A  + (size_t)(m0 + row) * K + (k0 + scol), ldsA + c * 512);
      gload_lds16(Bt + (size_t)(n0 + row) * K + (k0 + scol), ldsB + c * 512);
    }
    __syncthreads();
    #pragma unroll
    for (int ks = 0; ks < 2; ++ks) {
      bf16x8 af[4], bfv[4];
      #pragma unroll
      for (int mi = 0; mi < 4; ++mi)
        af[mi] = *(const bf16x8*)(ldsA + (wr * 64 + mi * 16 + lrow) * 64 + ks * 32 + lk);
      #pragma unroll
      for (int ni = 0; ni < 4; ++ni)
        bfv[ni] = *(const bf16x8*)(ldsB + (wc * 64 + ni * 16 + lrow) * 64 + ks * 32 + lk);
      #pragma unroll
      for (int mi = 0; mi < 4; ++mi)
        #pragma unroll
        for (int ni = 0; ni < 4; ++ni)
          acc[mi][ni] = __builtin_amdgcn_mfma_f32_16x16x32_bf16(af[mi], bfv[ni], acc[mi][ni], 0, 0, 0);
    }
  }

  #pragma unroll
  for (int mi = 0; mi < 4; ++mi) {
    const int rbase = m0 + wr * 64 + mi * 16 + (lane >> 4) * 4;
    #pragma unroll
    for (int ni = 0; ni < 4; ++ni) {
      const int col = n0 + wc * 64 + ni * 16 + lrow;
      if constexpr (EPI == 0) {
        const float bv = bias[col];
        // scale folds softmax 1/sqrt(64) AND log2(e) so attention uses exp2
        #pragma unroll
        for (int j = 0; j < 4; ++j)
          ((bf16_t*)out0)[(size_t)(rbase + j) * N + col] =
              (__bf16)((acc[mi][ni][j] + bv) * 0.18033688011112042f);
      } else if constexpr (EPI == 1) {
        const int hh = col >> 7, cbit = (col >> 6) & 1, d = col & 63;
        const float bv = bias[hh * 128 + d * 2 + cbit];
        #pragma unroll
        for (int j = 0; j < 4; ++j) {
          const int row = rbase + j;
          const int bi = row >> 11, lc = row & 2047;
          const float val = acc[mi][ni][j] + bv;
          if (cbit == 0)
            ((bf16_t*)out0)[((size_t)(bi * 16 + hh) * 2048 + lc) * 64 + d] = (__bf16)val;
          else
            ((bf16_t*)out1)[((size_t)(bi * 16 + hh) * 64 + d) * 2048 + lc] = (__bf16)val;
        }
      } else {
        const float bv = bias[col];
        #pragma unroll
        for (int j = 0; j < 4; ++j)
          ((float*)out0)[(size_t)(rbase + j) * N + col] = acc[mi][ni][j] + bv;
      }
    }
  }
}

// ---------------- flash attention v8: v7 + exact defer-max + exp2 softmax ----------------
// v7 (LDS-staged counted-vmcnt pipeline) was VALU-bound: 49% VALUBusy vs 14%
// MfmaUtil. Two exact/near-exact VALU cuts:
//  (1) exact defer-max: skip the rescale block when no lane saw a new max
//      (fac would be exp2(0)=1 for all -> multiply-by-1.0 identity, bitwise
//      exact; ~75% of iters skip ~35 VALU ops).
//  (2) exp2 softmax: log2(e) folded into the Q pre-scale (EPI0), so
//      __expf (mul+exp) becomes exp2f (exp only): -16 v_mul per iter.
__global__ __launch_bounds__(256, 2)
void attn_kernel(const bf16_t* __restrict__ q, const bf16_t* __restrict__ k,
                 const bf16_t* __restrict__ vt, bf16_t* __restrict__ o) {
  __shared__ __attribute__((aligned(16))) bf16_t stage[4][2][4096]; // per wave: [buf][K 2048 | V 2048]
  __shared__ float Osh[64][32];          // [d][q] f32
  __shared__ float Msh[4][32], Lsh[4][32];

  const int tid  = threadIdx.x;
  const int wave = tid >> 6, lane = tid & 63;
  const int li = lane & 31, hi = lane >> 5;

  // XCD-clustered decode: 8 XCDs x (4 heads x 64 q-tiles), bijective
  const int bid  = blockIdx.x;
  const int xcd  = bid & 7, slot = bid >> 3;
  const int bh   = xcd * 4 + (slot >> 6);
  const int qt   = slot & 63;
  const int b    = bh >> 4, h = bh & 15;

  bf16x8 qa[4];
  {
    const bf16_t* qp = q + (size_t)(b * LQ_ + qt * 32 + li) * 1024 + h * 64 + hi * 8;
    #pragma unroll
    for (int ks = 0; ks < 4; ++ks) qa[ks] = *(const bf16x8*)(qp + ks * 16);
  }
  // drain Q loads so vmcnt below counts only stage loads
  asm volatile("s_waitcnt vmcnt(0)" ::: "memory");

  const int kv0 = wave * (LC_ / 4);
  const bf16_t* kbase = k  + (size_t)bh * LC_ * 64 + (size_t)kv0 * 64;
  const bf16_t* vbase = vt + (size_t)bh * 64 * LC_ + kv0;

  // inverse-swizzled per-lane source offsets (elements)
  const int krow_l = lane >> 3, kcol_l = (lane & 7) ^ (krow_l & 7);
  const int vrow_l = lane >> 2, vcol_l = (lane & 3) ^ ((lane >> 3) & 3);
  const size_t koff = (size_t)krow_l * 64 + (size_t)kcol_l * 8;
  const size_t voff = (size_t)vrow_l * 2048 + (size_t)vcol_l * 8;

  bf16_t* lk0 = &stage[wave][0][0];
  bf16_t* lv0 = &stage[wave][0][2048];
  bf16_t* lk1 = &stage[wave][1][0];
  bf16_t* lv1 = &stage[wave][1][2048];

#define STAGE_CHUNK(T, LK, LV) do {                                              \
    const bf16_t* kc_ = kbase + (size_t)(T) * 2048;                              \
    const bf16_t* vc_ = vbase + (size_t)(T) * 32;                                \
    _Pragma("unroll")                                                            \
    for (int i_ = 0; i_ < 4; ++i_)                                               \
      gload_lds16(kc_ + koff + (size_t)i_ * 512, (LK) + i_ * 512);               \
    _Pragma("unroll")                                                            \
    for (int i_ = 0; i_ < 4; ++i_)                                               \
      gload_lds16(vc_ + voff + (size_t)i_ * 16 * 2048, (LV) + i_ * 512);         \
  } while (0)

  f32x16 oacc[2] = {};
  float m_run = -1e30f, l_run = 0.f;

  STAGE_CHUNK(0, lk0, lv0);
  STAGE_CHUNK(1, lk1, lv1);

  #pragma unroll 1
  for (int t = 0; t < 16; ++t) {
    bf16_t* lk = (t & 1) ? lk1 : lk0;
    bf16_t* lv = (t & 1) ? lv1 : lv0;

    // chunk t ready when only the 8 newer (chunk t+1) loads remain in flight
    asm volatile("s_waitcnt vmcnt(8)" ::: "memory");
    __builtin_amdgcn_sched_barrier(0);

    bf16x8 kf[4], vf[2][2];
    #pragma unroll
    for (int ks = 0; ks < 4; ++ks)
      kf[ks] = *(const bf16x8*)(lk + li * 64 + (((hi + ks * 2) ^ (li & 7)) * 8));
    #pragma unroll
    for (int dt = 0; dt < 2; ++dt)
      #pragma unroll
      for (int ks2 = 0; ks2 < 2; ++ks2)
        vf[dt][ks2] = *(const bf16x8*)(lv + (dt * 32 + li) * 32 + (((ks2 * 2 + hi) ^ ((li >> 1) & 3)) * 8));

    // frags in regs before overwriting this buffer
    asm volatile("s_waitcnt lgkmcnt(0)" ::: "memory");
    __builtin_amdgcn_sched_barrier(0);

    int t2 = t + 2; if (t2 > 15) t2 = 15;   // clamped restage keeps vmcnt counts uniform
    STAGE_CHUNK(t2, lk, lv);

    // ---- compute ----
    f32x16 sacc = {};
    #pragma unroll
    for (int ks = 0; ks < 4; ++ks)
      sacc = __builtin_amdgcn_mfma_f32_32x32x16_bf16(kf[ks], qa[ks], sacc, 0, 0, 0);

    float pm = sacc[0];
    #pragma unroll
    for (int r = 1; r < 16; ++r) pm = fmaxf(pm, sacc[r]);
    pm = fmaxf(pm, __shfl_xor(pm, 32, 64));

    // exact defer-max: skip entirely if no lane has a new max (fac==1 for all)
    if (!__all(pm <= m_run)) {
      const float mnew = fmaxf(m_run, pm);
      const float fac  = exp2f(m_run - mnew);
      l_run *= fac;
      #pragma unroll
      for (int dt = 0; dt < 2; ++dt)
        #pragma unroll
        for (int r = 0; r < 16; ++r) oacc[dt][r] *= fac;
      m_run = mnew;
    }

    float pv[16]; float ps = 0.f;
    #pragma unroll
    for (int r = 0; r < 16; ++r) { pv[r] = exp2f(sacc[r] - m_run); ps += pv[r]; }
    ps += __shfl_xor(ps, 32, 64);
    l_run += ps;

    unsigned pk[8];
    #pragma unroll
    for (int i = 0; i < 8; ++i) pk[i] = pack2(pv[2 * i], pv[2 * i + 1]);

    unsigned w[8];
    #pragma unroll
    for (int g2 = 0; g2 < 2; ++g2) {
      const int bidx = g2 * 4;
      const unsigned a0 = pk[bidx + 0], a1 = pk[bidx + 1];
      const unsigned b0 = pk[bidx + 2], b1 = pk[bidx + 3];
      const unsigned xa0 = __shfl_xor(a0, 32, 64), xa1 = __shfl_xor(a1, 32, 64);
      const unsigned xb0 = __shfl_xor(b0, 32, 64), xb1 = __shfl_xor(b1, 32, 64);
      w[bidx + 0] = hi ? xb0 : a0;
      w[bidx + 1] = hi ? xb1 : a1;
      w[bidx + 2] = hi ? b0  : xa0;
      w[bidx + 3] = hi ? b1  : xa1;
    }
    const u32x4 pw0 = {w[0], w[1], w[2], w[3]};
    const u32x4 pw1 = {w[4], w[5], w[6], w[7]};
    const bf16x8 pb0 = __builtin_bit_cast(bf16x8, pw0);
    const bf16x8 pb1 = __builtin_bit_cast(bf16x8, pw1);

    #pragma unroll
    for (int dt = 0; dt < 2; ++dt) {
      oacc[dt] = __builtin_amdgcn_mfma_f32_32x32x16_bf16(vf[dt][0], pb0, oacc[dt], 0, 0, 0);
      oacc[dt] = __builtin_amdgcn_mfma_f32_32x32x16_bf16(vf[dt][1], pb1, oacc[dt], 0, 0, 0);
    }
  }
#undef STAGE_CHUNK

  // ---- deterministic in-block merge of the 4 KV-split partials ----
  if (hi == 0) { Msh[wave][li] = m_run; Lsh[wave][li] = l_run; }
  __syncthreads();

  float mg = Msh[0][li];
  #pragma unroll
  for (int s = 1; s < 4; ++s) mg = fmaxf(mg, Msh[s][li]);
  const float fac = exp2f(m_run - mg);
  #pragma unroll
  for (int dt = 0; dt < 2; ++dt)
    #pragma unroll
    for (int r = 0; r < 16; ++r) oacc[dt][r] *= fac;

  #pragma unroll
  for (int ss = 0; ss < 4; ++ss) {
    if (wave == ss) {
      #pragma unroll
      for (int dt = 0; dt < 2; ++dt)
        #pragma unroll
        for (int r = 0; r < 16; ++r) {
          const int d = dt * 32 + (r & 3) + 8 * (r >> 2) + 4 * hi;
          if (ss == 0) Osh[d][li] = oacc[dt][r];
          else         Osh[d][li] += oacc[dt][r];
        }
    }
    __syncthreads();
  }

  // final: normalize + coalesced store
  const int qq = tid >> 3, c8 = (tid & 7) * 8;
  float mg2 = Msh[0][qq];
  #pragma unroll
  for (int s = 1; s < 4; ++s) mg2 = fmaxf(mg2, Msh[s][qq]);
  float lg = 0.f;
  #pragma unroll
  for (int s = 0; s < 4; ++s) lg += Lsh[s][qq] * exp2f(Msh[s][qq] - mg2);
  const float rl = 1.f / lg;

  u32x4 ow;
  #pragma unroll
  for (int j = 0; j < 4; ++j)
    ow[j] = pack2(Osh[c8 + 2 * j][qq] * rl, Osh[c8 + 2 * j + 1][qq] * rl);
  *(u32x4*)(o + (size_t)(b * LQ_ + qt * 32 + qq) * 1024 + h * 64 + c8) = ow;
}

extern "C" void kernel_launch(void* const* d_in, const int* in_sizes, int n_in,
                              void* d_out, int out_size, void* d_ws, size_t ws_size,
                              hipStream_t stream) {
  const float* query   = (const float*)d_in[0];
  const float* context = (const float*)d_in[1];
  const float* Wq      = (const float*)d_in[2];
  const float* bq      = (const float*)d_in[3];
  const float* Wkv     = (const float*)d_in[4];
  const float* bkv     = (const float*)d_in[5];
  const float* Wout    = (const float*)d_in[6];
  const float* bout    = (const float*)d_in[7];

  char* p = (char*)d_ws;
  bf16_t* queryb = (bf16_t*)p; p += (size_t)4096 * 1024 * 2;
  bf16_t* ctxb   = (bf16_t*)p; p += (size_t)4096 * 1024 * 2;
  bf16_t* Wq_t   = (bf16_t*)p; p += (size_t)1024 * 1024 * 2;
  bf16_t* Wkv_t  = (bf16_t*)p; p += (size_t)2048 * 1024 * 2;
  bf16_t* Wout_t = (bf16_t*)p; p += (size_t)1024 * 1024 * 2;
  bf16_t* q_s    = (bf16_t*)p; p += (size_t)4096 * 1024 * 2;
  bf16_t* k_s    = (bf16_t*)p; p += (size_t)4096 * 1024 * 2;
  bf16_t* v_t    = (bf16_t*)p; p += (size_t)4096 * 1024 * 2;
  bf16_t* attnb  = (bf16_t*)p; p += (size_t)4096 * 1024 * 2;
  if ((size_t)(p - (char*)d_ws) > ws_size) return;

  cvt_bf16_kernel<<<4096, 256, 0, stream>>>(query, queryb, 4096 * 1024 / 4);
  cvt_bf16_kernel<<<4096, 256, 0, stream>>>(context, ctxb, 4096 * 1024 / 4);
  transpose_cvt_kernel<<<dim3(32, 32), 256, 0, stream>>>(Wq,   Wq_t,   1024, 1024, 0);
  transpose_cvt_kernel<<<dim3(64, 32), 256, 0, stream>>>(Wkv,  Wkv_t,  1024, 2048, 1);
  transpose_cvt_kernel<<<dim3(32, 32), 256, 0, stream>>>(Wout, Wout_t, 1024, 1024, 0);

  gemm_bt_kernel<0><<<dim3(8, 32),  256, 0, stream>>>(queryb, Wq_t,  bq,  q_s,  nullptr, 1024, 1024);
  gemm_bt_kernel<1><<<dim3(16, 32), 256, 0, stream>>>(ctxb,   Wkv_t, bkv, k_s,  v_t,     2048, 1024);
  attn_kernel<<<dim3(2048), 256, 0, stream>>>(q_s, k_s, v_t, attnb);
  gemm_bt_kernel<2><<<dim3(8, 32),  256, 0, stream>>>(attnb,  Wout_t, bout, d_out, nullptr, 1024, 1024);
}

// Round 10
// 191.658 us; speedup vs baseline: 1.0525x; 1.0525x over previous
//
#include <hip/hip_runtime.h>
#include <hip/hip_bf16.h>
#include <stdint.h>

typedef __bf16 bf16_t;
typedef __bf16 bf16x8 __attribute__((ext_vector_type(8)));
typedef __bf16 bf16x4_t __attribute__((ext_vector_type(4)));
typedef float f32x4 __attribute__((ext_vector_type(4)));
typedef float f32x16 __attribute__((ext_vector_type(16)));
typedef unsigned int u32x4 __attribute__((ext_vector_type(4)));

#define B_   2
#define H_   16
#define D_   64
#define LQ_  2048
#define LC_  2048
#define M_   1024

// raw v_exp_f32 (2^x, ~1 ulp). NOT exp2f (= __ocml_exp2_f32, ~5 VALU ops,
// the round-8 regression). permlane32_swap is BANNED (2 failed derivations);
// all cross-lane ops use the round-7-proven __shfl_xor forms.
#define EXP2(x) __builtin_amdgcn_exp2f(x)

__device__ __forceinline__ void gload_lds16(const void* g, void* l) {
  __builtin_amdgcn_global_load_lds((__attribute__((address_space(1))) unsigned int*)(g),
                                   (__attribute__((address_space(3))) unsigned int*)(l),
                                   16, 0, 0);
}

__device__ __forceinline__ unsigned pack2(float a, float b) {
  __bf16 x = (__bf16)a, y = (__bf16)b;
  unsigned short ux = __builtin_bit_cast(unsigned short, x);
  unsigned short uy = __builtin_bit_cast(unsigned short, y);
  return (unsigned)ux | ((unsigned)uy << 16);
}

// ---------------- fp32 -> bf16 elementwise (vectorized) ----------------
__global__ void cvt_bf16_kernel(const float* __restrict__ in, bf16_t* __restrict__ out, int n4) {
  int i = blockIdx.x * blockDim.x + threadIdx.x;
  if (i < n4) {
    const float4 f = ((const float4*)in)[i];
    bf16x4_t o4;
    o4[0] = (__bf16)f.x; o4[1] = (__bf16)f.y; o4[2] = (__bf16)f.z; o4[3] = (__bf16)f.w;
    ((bf16x4_t*)out)[i] = o4;
  }
}

// ---------------- transpose + convert weights: out[n][k] = in[k][n] ----------------
__global__ void transpose_cvt_kernel(const float* __restrict__ in, bf16_t* __restrict__ out,
                                     int K, int N, int kvperm) {
  __shared__ float tile[32][33];
  const int n0 = blockIdx.x * 32, k0 = blockIdx.y * 32;
  const int tx = threadIdx.x & 31, ty = threadIdx.x >> 5;
  #pragma unroll
  for (int r = ty; r < 32; r += 8)
    tile[r][tx] = in[(size_t)(k0 + r) * N + (n0 + tx)];
  __syncthreads();
  #pragma unroll
  for (int r = ty; r < 32; r += 8) {
    const int n = n0 + r;
    const int orow = kvperm ? ((n & ~127) | ((n & 1) << 6) | ((n >> 1) & 63)) : n;
    out[(size_t)orow * K + (k0 + tx)] = (__bf16)tile[tx][r];
  }
}

// ---------------- GEMM: C[M,N] = A[M,K] @ Bt[N,K]^T, m97 structure ----------------
template <int EPI>
__global__ __launch_bounds__(256)
void gemm_bt_kernel(const bf16_t* __restrict__ A, const bf16_t* __restrict__ Bt,
                    const float* __restrict__ bias,
                    void* __restrict__ out0, void* __restrict__ out1,
                    int N, int K) {
  __shared__ __attribute__((aligned(16))) bf16_t ldsA[128 * 64];
  __shared__ __attribute__((aligned(16))) bf16_t ldsB[128 * 64];
  const int tid  = threadIdx.x;
  const int wave = tid >> 6, lane = tid & 63;
  const int m0 = blockIdx.y * 128, n0 = blockIdx.x * 128;
  const int wr = wave >> 1, wc = wave & 1;
  const int lrow = lane & 15, lk = (lane >> 4) * 8;
  const int srow = lane >> 3, scol = (lane & 7) * 8;

  f32x4 acc[4][4] = {};

  for (int k0 = 0; k0 < K; k0 += 64) {
    __syncthreads();
    #pragma unroll
    for (int i = 0; i < 4; ++i) {
      const int c = wave * 4 + i;
      const int row = c * 8 + srow;
      gload_lds16(A  + (size_t)(m0 + row) * K + (k0 + scol), ldsA + c * 512);
      gload_lds16(Bt + (size_t)(n0 + row) * K + (k0 + scol), ldsB + c * 512);
    }
    __syncthreads();
    #pragma unroll
    for (int ks = 0; ks < 2; ++ks) {
      bf16x8 af[4], bfv[4];
      #pragma unroll
      for (int mi = 0; mi < 4; ++mi)
        af[mi] = *(const bf16x8*)(ldsA + (wr * 64 + mi * 16 + lrow) * 64 + ks * 32 + lk);
      #pragma unroll
      for (int ni = 0; ni < 4; ++ni)
        bfv[ni] = *(const bf16x8*)(ldsB + (wc * 64 + ni * 16 + lrow) * 64 + ks * 32 + lk);
      #pragma unroll
      for (int mi = 0; mi < 4; ++mi)
        #pragma unroll
        for (int ni = 0; ni < 4; ++ni)
          acc[mi][ni] = __builtin_amdgcn_mfma_f32_16x16x32_bf16(af[mi], bfv[ni], acc[mi][ni], 0, 0, 0);
    }
  }

  #pragma unroll
  for (int mi = 0; mi < 4; ++mi) {
    const int rbase = m0 + wr * 64 + mi * 16 + (lane >> 4) * 4;
    #pragma unroll
    for (int ni = 0; ni < 4; ++ni) {
      const int col = n0 + wc * 64 + ni * 16 + lrow;
      if constexpr (EPI == 0) {
        const float bv = bias[col];
        // scale folds softmax 1/sqrt(64) AND log2(e) so attention uses exp2
        #pragma unroll
        for (int j = 0; j < 4; ++j)
          ((bf16_t*)out0)[(size_t)(rbase + j) * N + col] =
              (__bf16)((acc[mi][ni][j] + bv) * 0.18033688011112042f);
      } else if constexpr (EPI == 1) {
        const int hh = col >> 7, cbit = (col >> 6) & 1, d = col & 63;
        const float bv = bias[hh * 128 + d * 2 + cbit];
        #pragma unroll
        for (int j = 0; j < 4; ++j) {
          const int row = rbase + j;
          const int bi = row >> 11, lc = row & 2047;
          const float val = acc[mi][ni][j] + bv;
          if (cbit == 0)
            ((bf16_t*)out0)[((size_t)(bi * 16 + hh) * 2048 + lc) * 64 + d] = (__bf16)val;
          else
            ((bf16_t*)out1)[((size_t)(bi * 16 + hh) * 64 + d) * 2048 + lc] = (__bf16)val;
        }
      } else {
        const float bv = bias[col];
        #pragma unroll
        for (int j = 0; j < 4; ++j)
          ((float*)out0)[(size_t)(rbase + j) * N + col] = acc[mi][ni][j] + bv;
      }
    }
  }
}

// ---------------- flash attention v10: round-8 math (proven) + raw v_exp ----------------
// = v7 LDS-staged counted-vmcnt pipeline + exact defer-max + exp2 softmax
// (log2e folded in EPI0), with EXP2 mapped to the 1-op builtin instead of
// the ~5-op __ocml_exp2_f32 that caused the round-8 regression.
// All cross-lane exchanges are the round-7-proven __shfl_xor forms.
__global__ __launch_bounds__(256, 2)
void attn_kernel(const bf16_t* __restrict__ q, const bf16_t* __restrict__ k,
                 const bf16_t* __restrict__ vt, bf16_t* __restrict__ o) {
  __shared__ __attribute__((aligned(16))) bf16_t stage[4][2][4096]; // per wave: [buf][K 2048 | V 2048]
  __shared__ float Osh[64][32];          // [d][q] f32
  __shared__ float Msh[4][32], Lsh[4][32];

  const int tid  = threadIdx.x;
  const int wave = tid >> 6, lane = tid & 63;
  const int li = lane & 31, hi = lane >> 5;

  // XCD-clustered decode: 8 XCDs x (4 heads x 64 q-tiles), bijective
  const int bid  = blockIdx.x;
  const int xcd  = bid & 7, slot = bid >> 3;
  const int bh   = xcd * 4 + (slot >> 6);
  const int qt   = slot & 63;
  const int b    = bh >> 4, h = bh & 15;

  bf16x8 qa[4];
  {
    const bf16_t* qp = q + (size_t)(b * LQ_ + qt * 32 + li) * 1024 + h * 64 + hi * 8;
    #pragma unroll
    for (int ks = 0; ks < 4; ++ks) qa[ks] = *(const bf16x8*)(qp + ks * 16);
  }
  // drain Q loads so vmcnt below counts only stage loads
  asm volatile("s_waitcnt vmcnt(0)" ::: "memory");

  const int kv0 = wave * (LC_ / 4);
  const bf16_t* kbase = k  + (size_t)bh * LC_ * 64 + (size_t)kv0 * 64;
  const bf16_t* vbase = vt + (size_t)bh * 64 * LC_ + kv0;

  // inverse-swizzled per-lane source offsets (elements)
  const int krow_l = lane >> 3, kcol_l = (lane & 7) ^ (krow_l & 7);
  const int vrow_l = lane >> 2, vcol_l = (lane & 3) ^ ((lane >> 3) & 3);
  const size_t koff = (size_t)krow_l * 64 + (size_t)kcol_l * 8;
  const size_t voff = (size_t)vrow_l * 2048 + (size_t)vcol_l * 8;

  bf16_t* lk0 = &stage[wave][0][0];
  bf16_t* lv0 = &stage[wave][0][2048];
  bf16_t* lk1 = &stage[wave][1][0];
  bf16_t* lv1 = &stage[wave][1][2048];

#define STAGE_CHUNK(T, LK, LV) do {                                              \
    const bf16_t* kc_ = kbase + (size_t)(T) * 2048;                              \
    const bf16_t* vc_ = vbase + (size_t)(T) * 32;                                \
    _Pragma("unroll")                                                            \
    for (int i_ = 0; i_ < 4; ++i_)                                               \
      gload_lds16(kc_ + koff + (size_t)i_ * 512, (LK) + i_ * 512);               \
    _Pragma("unroll")                                                            \
    for (int i_ = 0; i_ < 4; ++i_)                                               \
      gload_lds16(vc_ + voff + (size_t)i_ * 16 * 2048, (LV) + i_ * 512);         \
  } while (0)

  f32x16 oacc[2] = {};
  float m_run = -1e30f, l_run = 0.f;

  STAGE_CHUNK(0, lk0, lv0);
  STAGE_CHUNK(1, lk1, lv1);

  #pragma unroll 1
  for (int t = 0; t < 16; ++t) {
    bf16_t* lk = (t & 1) ? lk1 : lk0;
    bf16_t* lv = (t & 1) ? lv1 : lv0;

    // chunk t ready when only the 8 newer (chunk t+1) loads remain in flight
    asm volatile("s_waitcnt vmcnt(8)" ::: "memory");
    __builtin_amdgcn_sched_barrier(0);

    bf16x8 kf[4], vf[2][2];
    #pragma unroll
    for (int ks = 0; ks < 4; ++ks)
      kf[ks] = *(const bf16x8*)(lk + li * 64 + (((hi + ks * 2) ^ (li & 7)) * 8));
    #pragma unroll
    for (int dt = 0; dt < 2; ++dt)
      #pragma unroll
      for (int ks2 = 0; ks2 < 2; ++ks2)
        vf[dt][ks2] = *(const bf16x8*)(lv + (dt * 32 + li) * 32 + (((ks2 * 2 + hi) ^ ((li >> 1) & 3)) * 8));

    // frags in regs before overwriting this buffer
    asm volatile("s_waitcnt lgkmcnt(0)" ::: "memory");
    __builtin_amdgcn_sched_barrier(0);

    int t2 = t + 2; if (t2 > 15) t2 = 15;   // clamped restage keeps vmcnt counts uniform
    STAGE_CHUNK(t2, lk, lv);

    // ---- compute ----
    f32x16 sacc = {};
    #pragma unroll
    for (int ks = 0; ks < 4; ++ks)
      sacc = __builtin_amdgcn_mfma_f32_32x32x16_bf16(kf[ks], qa[ks], sacc, 0, 0, 0);

    float pm = sacc[0];
    #pragma unroll
    for (int r = 1; r < 16; ++r) pm = fmaxf(pm, sacc[r]);
    pm = fmaxf(pm, __shfl_xor(pm, 32, 64));

    // exact defer-max: skip entirely if no lane has a new max (fac==1 for all)
    if (!__all(pm <= m_run)) {
      const float mnew = fmaxf(m_run, pm);
      const float fac  = EXP2(m_run - mnew);
      l_run *= fac;
      #pragma unroll
      for (int dt = 0; dt < 2; ++dt)
        #pragma unroll
        for (int r = 0; r < 16; ++r) oacc[dt][r] *= fac;
      m_run = mnew;
    }

    float pv[16]; float ps = 0.f;
    #pragma unroll
    for (int r = 0; r < 16; ++r) { pv[r] = EXP2(sacc[r] - m_run); ps += pv[r]; }
    ps += __shfl_xor(ps, 32, 64);
    l_run += ps;

    unsigned pk[8];
    #pragma unroll
    for (int i = 0; i < 8; ++i) pk[i] = pack2(pv[2 * i], pv[2 * i + 1]);

    unsigned w[8];
    #pragma unroll
    for (int g2 = 0; g2 < 2; ++g2) {
      const int bidx = g2 * 4;
      const unsigned a0 = pk[bidx + 0], a1 = pk[bidx + 1];
      const unsigned b0 = pk[bidx + 2], b1 = pk[bidx + 3];
      const unsigned xa0 = __shfl_xor(a0, 32, 64), xa1 = __shfl_xor(a1, 32, 64);
      const unsigned xb0 = __shfl_xor(b0, 32, 64), xb1 = __shfl_xor(b1, 32, 64);
      w[bidx + 0] = hi ? xb0 : a0;
      w[bidx + 1] = hi ? xb1 : a1;
      w[bidx + 2] = hi ? b0  : xa0;
      w[bidx + 3] = hi ? b1  : xa1;
    }
    const u32x4 pw0 = {w[0], w[1], w[2], w[3]};
    const u32x4 pw1 = {w[4], w[5], w[6], w[7]};
    const bf16x8 pb0 = __builtin_bit_cast(bf16x8, pw0);
    const bf16x8 pb1 = __builtin_bit_cast(bf16x8, pw1);

    #pragma unroll
    for (int dt = 0; dt < 2; ++dt) {
      oacc[dt] = __builtin_amdgcn_mfma_f32_32x32x16_bf16(vf[dt][0], pb0, oacc[dt], 0, 0, 0);
      oacc[dt] = __builtin_amdgcn_mfma_f32_32x32x16_bf16(vf[dt][1], pb1, oacc[dt], 0, 0, 0);
    }
  }
#undef STAGE_CHUNK

  // ---- deterministic in-block merge of the 4 KV-split partials ----
  if (hi == 0) { Msh[wave][li] = m_run; Lsh[wave][li] = l_run; }
  __syncthreads();

  float mg = Msh[0][li];
  #pragma unroll
  for (int s = 1; s < 4; ++s) mg = fmaxf(mg, Msh[s][li]);
  const float fac = EXP2(m_run - mg);
  #pragma unroll
  for (int dt = 0; dt < 2; ++dt)
    #pragma unroll
    for (int r = 0; r < 16; ++r) oacc[dt][r] *= fac;

  #pragma unroll
  for (int ss = 0; ss < 4; ++ss) {
    if (wave == ss) {
      #pragma unroll
      for (int dt = 0; dt < 2; ++dt)
        #pragma unroll
        for (int r = 0; r < 16; ++r) {
          const int d = dt * 32 + (r & 3) + 8 * (r >> 2) + 4 * hi;
          if (ss == 0) Osh[d][li] = oacc[dt][r];
          else         Osh[d][li] += oacc[dt][r];
        }
    }
    __syncthreads();
  }

  // final: normalize + coalesced store
  const int qq = tid >> 3, c8 = (tid & 7) * 8;
  float mg2 = Msh[0][qq];
  #pragma unroll
  for (int s = 1; s < 4; ++s) mg2 = fmaxf(mg2, Msh[s][qq]);
  float lg = 0.f;
  #pragma unroll
  for (int s = 0; s < 4; ++s) lg += Lsh[s][qq] * EXP2(Msh[s][qq] - mg2);
  const float rl = 1.f / lg;

  u32x4 ow;
  #pragma unroll
  for (int j = 0; j < 4; ++j)
    ow[j] = pack2(Osh[c8 + 2 * j][qq] * rl, Osh[c8 + 2 * j + 1][qq] * rl);
  *(u32x4*)(o + (size_t)(b * LQ_ + qt * 32 + qq) * 1024 + h * 64 + c8) = ow;
}

extern "C" void kernel_launch(void* const* d_in, const int* in_sizes, int n_in,
                              void* d_out, int out_size, void* d_ws, size_t ws_size,
                              hipStream_t stream) {
  const float* query   = (const float*)d_in[0];
  const float* context = (const float*)d_in[1];
  const float* Wq      = (const float*)d_in[2];
  const float* bq      = (const float*)d_in[3];
  const float* Wkv     = (const float*)d_in[4];
  const float* bkv     = (const float*)d_in[5];
  const float* Wout    = (const float*)d_in[6];
  const float* bout    = (const float*)d_in[7];

  char* p = (char*)d_ws;
  bf16_t* queryb = (bf16_t*)p; p += (size_t)4096 * 1024 * 2;
  bf16_t* ctxb   = (bf16_t*)p; p += (size_t)4096 * 1024 * 2;
  bf16_t* Wq_t   = (bf16_t*)p; p += (size_t)1024 * 1024 * 2;
  bf16_t* Wkv_t  = (bf16_t*)p; p += (size_t)2048 * 1024 * 2;
  bf16_t* Wout_t = (bf16_t*)p; p += (size_t)1024 * 1024 * 2;
  bf16_t* q_s    = (bf16_t*)p; p += (size_t)4096 * 1024 * 2;
  bf16_t* k_s    = (bf16_t*)p; p += (size_t)4096 * 1024 * 2;
  bf16_t* v_t    = (bf16_t*)p; p += (size_t)4096 * 1024 * 2;
  bf16_t* attnb  = (bf16_t*)p; p += (size_t)4096 * 1024 * 2;
  if ((size_t)(p - (char*)d_ws) > ws_size) return;

  cvt_bf16_kernel<<<4096, 256, 0, stream>>>(query, queryb, 4096 * 1024 / 4);
  cvt_bf16_kernel<<<4096, 256, 0, stream>>>(context, ctxb, 4096 * 1024 / 4);
  transpose_cvt_kernel<<<dim3(32, 32), 256, 0, stream>>>(Wq,   Wq_t,   1024, 1024, 0);
  transpose_cvt_kernel<<<dim3(64, 32), 256, 0, stream>>>(Wkv,  Wkv_t,  1024, 2048, 1);
  transpose_cvt_kernel<<<dim3(32, 32), 256, 0, stream>>>(Wout, Wout_t, 1024, 1024, 0);

  gemm_bt_kernel<0><<<dim3(8, 32),  256, 0, stream>>>(queryb, Wq_t,  bq,  q_s,  nullptr, 1024, 1024);
  gemm_bt_kernel<1><<<dim3(16, 32), 256, 0, stream>>>(ctxb,   Wkv_t, bkv, k_s,  v_t,     2048, 1024);
  attn_kernel<<<dim3(2048), 256, 0, stream>>>(q_s, k_s, v_t, attnb);
  gemm_bt_kernel<2><<<dim3(8, 32),  256, 0, stream>>>(attnb,  Wout_t, bout, d_out, nullptr, 1024, 1024);
}